// Round 1
// baseline (2832.483 us; speedup 1.0000x reference)
//
#include <hip/hip_runtime.h>
#include <math.h>

namespace {

constexpr int NN = 100000;
constexpr int NE = 1600000;
constexpr float EPS = 1e-5f;

__device__ __forceinline__ float leaky(float x) { return x > 0.f ? x : 0.01f * x; }

// ---------------- preprocessing: degrees, dinv, CSR-by-dst ----------------

__global__ __launch_bounds__(256) void k_init(int* __restrict__ deg, int* __restrict__ counter, int n) {
  int i = blockIdx.x * 256 + threadIdx.x;
  if (i < n) deg[i] = 1;          // self-loop
  if (i == 0) counter[0] = 0;
}

__global__ __launch_bounds__(256) void k_count(const int* __restrict__ dst, int* __restrict__ deg, int e) {
  int i = blockIdx.x * 256 + threadIdx.x;
  if (i < e) atomicAdd(&deg[dst[i]], 1);
}

// dinv = rsqrt(deg); allocate CSR slot ranges via wave-aggregated atomic
__global__ __launch_bounds__(256) void k_alloc(const int* __restrict__ deg, float* __restrict__ dinv,
                                               int* __restrict__ offsets, int* __restrict__ cursor,
                                               int* __restrict__ counter, int n) {
  int i = blockIdx.x * 256 + threadIdx.x;
  int lane = threadIdx.x & 63;
  int c = 0;
  if (i < n) {
    int d = deg[i];
    dinv[i] = rsqrtf((float)d);
    c = d - 1;                    // real in-edges only (self-loop handled analytically)
  }
  // wave inclusive scan
  int v = c;
#pragma unroll
  for (int s = 1; s < 64; s <<= 1) {
    int t = __shfl_up(v, s, 64);
    if (lane >= s) v += t;
  }
  int total = __shfl(v, 63, 64);
  int base = 0;
  if (lane == 63) base = atomicAdd(counter, total);
  base = __shfl(base, 63, 64);
  if (i < n) {
    int off = base + v - c;       // exclusive prefix
    offsets[i] = off;
    cursor[i] = off;
  }
}

__global__ __launch_bounds__(256) void k_fill(const int* __restrict__ src, const int* __restrict__ dst,
                                              const float* __restrict__ dinv, int* __restrict__ cursor,
                                              int* __restrict__ adj_src, float* __restrict__ adj_norm, int e) {
  int i = blockIdx.x * 256 + threadIdx.x;
  if (i < e) {
    int s = src[i], d = dst[i];
    int p = atomicAdd(&cursor[d], 1);
    adj_src[p] = s;
    adj_norm[p] = dinv[s] * dinv[d];
  }
}

// zero-pad gw1 [94][128] -> [96][128]
__global__ __launch_bounds__(256) void k_padw1(const float* __restrict__ gw1, float* __restrict__ w1p) {
  int i = blockIdx.x * 256 + threadIdx.x;
  if (i < 96 * 128) w1p[i] = (i < 94 * 128) ? gw1[i] : 0.f;
}

// ---------------- CNN encoder ----------------
// per node: in [1][100][5] -> conv(10,3x3)+leaky -> conv(20,3x2)+leaky -> conv(1,3x2) -> tanh -> H[94] (stride 96, cols 94,95 = 0)
// block = 256 threads = 4 waves = 4 nodes; all intermediates in LDS.
__global__ __launch_bounds__(256) void k_cnn(const float* __restrict__ x,
                                             const float* __restrict__ cw1, const float* __restrict__ cb1,
                                             const float* __restrict__ cw2, const float* __restrict__ cb2,
                                             const float* __restrict__ cw3, const float* __restrict__ cb3,
                                             float* __restrict__ H, int n) {
  __shared__ float w1s[90];
  __shared__ float b1s[10];
  __shared__ float w2s[1200];
  __shared__ float b2s[20];
  __shared__ float w3s[120];
  __shared__ float b3s;
  __shared__ float inb[4][500];
  __shared__ float c1[4][2940];   // [10][98][3]
  __shared__ float c2[4][3840];   // [20][96][2]

  int tid = threadIdx.x;
  if (tid < 90) w1s[tid] = cw1[tid];
  if (tid < 10) b1s[tid] = cb1[tid];
  for (int i = tid; i < 1200; i += 256) w2s[i] = cw2[i];
  if (tid < 20) b2s[tid] = cb2[tid];
  if (tid < 120) w3s[tid] = cw3[tid];
  if (tid == 0) b3s = cb3[0];

  int wv = tid >> 6;
  int lane = tid & 63;
  int node = blockIdx.x * 4 + wv;
  bool active = node < n;

  if (active) {
    const float* xp = x + (size_t)node * 500;
    for (int i = lane; i < 500; i += 64) inb[wv][i] = xp[i];
  }
  __syncthreads();

  if (active) {
    // conv1: each lane handles positions p = (h,w), computes all 10 co
    const float* in = inb[wv];
    float* c1p = c1[wv];
    for (int p = lane; p < 294; p += 64) {
      int h = p / 3, w = p - h * 3;
      float xv[9];
#pragma unroll
      for (int kh = 0; kh < 3; kh++)
#pragma unroll
        for (int kw = 0; kw < 3; kw++) xv[kh * 3 + kw] = in[(h + kh) * 5 + w + kw];
#pragma unroll
      for (int co = 0; co < 10; co++) {
        float a = b1s[co];
#pragma unroll
        for (int q = 0; q < 9; q++) a += xv[q] * w1s[co * 9 + q];
        c1p[(co * 98 + h) * 3 + w] = leaky(a);
      }
    }
  }
  __syncthreads();

  if (active) {
    // conv2: lane tile = 6h x 2w x 5co; 16 h-groups x 4 co-groups = 64 lanes
    float* c1p = c1[wv];
    float* c2p = c2[wv];
    int hg = lane & 15, cog = lane >> 4;
    int h0 = hg * 6, co0 = cog * 5;
    float acc[6][2][5];
#pragma unroll
    for (int a = 0; a < 6; a++)
#pragma unroll
      for (int b = 0; b < 2; b++)
#pragma unroll
        for (int c = 0; c < 5; c++) acc[a][b][c] = 0.f;
#pragma unroll 1
    for (int ci = 0; ci < 10; ci++) {
      float r[8][3];
      const float* base = c1p + (ci * 98 + h0) * 3;
#pragma unroll
      for (int i = 0; i < 8; i++)
#pragma unroll
        for (int j = 0; j < 3; j++) r[i][j] = base[i * 3 + j];
      float wt[5][6];
#pragma unroll
      for (int c = 0; c < 5; c++)
#pragma unroll
        for (int q = 0; q < 6; q++) wt[c][q] = w2s[((co0 + c) * 10 + ci) * 6 + q];
#pragma unroll
      for (int hh = 0; hh < 6; hh++)
#pragma unroll
        for (int w = 0; w < 2; w++)
#pragma unroll
          for (int c = 0; c < 5; c++)
            acc[hh][w][c] += r[hh][w] * wt[c][0] + r[hh][w + 1] * wt[c][1]
                           + r[hh + 1][w] * wt[c][2] + r[hh + 1][w + 1] * wt[c][3]
                           + r[hh + 2][w] * wt[c][4] + r[hh + 2][w + 1] * wt[c][5];
    }
#pragma unroll
    for (int hh = 0; hh < 6; hh++)
#pragma unroll
      for (int w = 0; w < 2; w++)
#pragma unroll
        for (int c = 0; c < 5; c++)
          c2p[((co0 + c) * 96 + h0 + hh) * 2 + w] = leaky(acc[hh][w][c] + b2s[co0 + c]);
  }
  __syncthreads();

  if (active) {
    // conv3 + tanh -> H
    float* c2p = c2[wv];
    float* Hp = H + (size_t)node * 96;
    for (int h = lane; h < 94; h += 64) {
      float a = b3s;
#pragma unroll
      for (int ci = 0; ci < 20; ci++) {
        const float* cb = c2p + (ci * 96 + h) * 2;
#pragma unroll
        for (int q = 0; q < 6; q++) a += cb[q] * w3s[ci * 6 + q];
      }
      Hp[h] = tanhf(a);
    }
    if (lane < 2) Hp[94 + lane] = 0.f;
  }
}

// ---------------- GEMM: C[M,FO-tile] = A[M,K] @ W[K,FO] ----------------
template <int K, int FO, int BN>
__global__ __launch_bounds__(256) void k_gemm(const float* __restrict__ A, const float* __restrict__ W,
                                              float* __restrict__ C, int M) {
  __shared__ float As[64][K + 1];
  __shared__ __align__(16) float Ws[K][BN];
  int tid = threadIdx.x;
  int row_base = blockIdx.x * 64;
  int col_base = blockIdx.y * BN;

  for (int idx = tid; idx < 64 * K; idx += 256) {
    int r = idx / K, k = idx - r * K;
    int row = row_base + r;
    As[r][k] = (row < M) ? A[(size_t)row * K + k] : 0.f;
  }
  for (int idx = tid; idx < K * BN; idx += 256) {
    int r = idx / BN, c = idx - r * BN;
    Ws[r][c] = W[r * FO + col_base + c];
  }
  __syncthreads();

  if constexpr (BN == 64) {
    int ty = tid >> 4, tx = tid & 15;
    float acc[4][4] = {};
#pragma unroll 4
    for (int k = 0; k < K; k++) {
      float a0 = As[ty * 4 + 0][k];
      float a1 = As[ty * 4 + 1][k];
      float a2 = As[ty * 4 + 2][k];
      float a3 = As[ty * 4 + 3][k];
      const float4 b = *(const float4*)&Ws[k][tx * 4];
      acc[0][0] += a0 * b.x; acc[0][1] += a0 * b.y; acc[0][2] += a0 * b.z; acc[0][3] += a0 * b.w;
      acc[1][0] += a1 * b.x; acc[1][1] += a1 * b.y; acc[1][2] += a1 * b.z; acc[1][3] += a1 * b.w;
      acc[2][0] += a2 * b.x; acc[2][1] += a2 * b.y; acc[2][2] += a2 * b.z; acc[2][3] += a2 * b.w;
      acc[3][0] += a3 * b.x; acc[3][1] += a3 * b.y; acc[3][2] += a3 * b.z; acc[3][3] += a3 * b.w;
    }
#pragma unroll
    for (int i = 0; i < 4; i++) {
      int row = row_base + ty * 4 + i;
      if (row < M) {
        float4 v = make_float4(acc[i][0], acc[i][1], acc[i][2], acc[i][3]);
        *(float4*)&C[(size_t)row * FO + col_base + tx * 4] = v;
      }
    }
  } else {  // BN == 16: thread = 1 row x 4 cols
    int ty = tid >> 2, tx = tid & 3;
    float acc[4] = {};
#pragma unroll 4
    for (int k = 0; k < K; k++) {
      float a = As[ty][k];
      const float4 b = *(const float4*)&Ws[k][tx * 4];
      acc[0] += a * b.x; acc[1] += a * b.y; acc[2] += a * b.z; acc[3] += a * b.w;
    }
    int row = row_base + ty;
    if (row < M) *(float4*)&C[(size_t)row * FO + col_base + tx * 4] = make_float4(acc[0], acc[1], acc[2], acc[3]);
  }
}

// ---------------- aggregation + bias + BN (+tanh | +softmax) ----------------
template <int FO, bool SOFT>
__global__ __launch_bounds__(256) void k_agg(const float* __restrict__ XW,
                                             const int* __restrict__ offsets, const int* __restrict__ deg,
                                             const int* __restrict__ adj_src, const float* __restrict__ adj_norm,
                                             const float* __restrict__ dinv,
                                             const float* __restrict__ gb, const float* __restrict__ bg,
                                             const float* __restrict__ bb, const float* __restrict__ bm,
                                             const float* __restrict__ bv,
                                             float* __restrict__ out, int n) {
  constexpr int NPB = 256 / FO;
  int tid = threadIdx.x;
  int li = tid / FO, col = tid % FO;
  int node = blockIdx.x * NPB + li;
  if (node >= n) return;

  float dv = dinv[node];
  float acc = XW[(size_t)node * FO + col] * dv * dv;  // self-loop
  int start = offsets[node];
  int cnt = deg[node] - 1;
  for (int e = 0; e < cnt; e++) {
    int s = adj_src[start + e];
    float nm = adj_norm[start + e];
    acc += XW[(size_t)s * FO + col] * nm;
  }
  float scale = bg[col] * rsqrtf(bv[col] + EPS);
  float v = (acc + gb[col] - bm[col]) * scale + bb[col];
  if constexpr (SOFT) {
    float mx = v;
#pragma unroll
    for (int m = 8; m; m >>= 1) mx = fmaxf(mx, __shfl_xor(mx, m, 16));
    float ex = expf(v - mx);
    float sm = ex;
#pragma unroll
    for (int m = 8; m; m >>= 1) sm += __shfl_xor(sm, m, 16);
    out[(size_t)node * FO + col] = ex / sm;
  } else {
    out[(size_t)node * FO + col] = tanhf(v);
  }
}

}  // namespace

extern "C" void kernel_launch(void* const* d_in, const int* in_sizes, int n_in,
                              void* d_out, int out_size, void* d_ws, size_t ws_size,
                              hipStream_t stream) {
  const float* x   = (const float*)d_in[0];
  const int*   ei  = (const int*)d_in[1];
  const float* cw1 = (const float*)d_in[2];
  const float* cb1 = (const float*)d_in[3];
  const float* cw2 = (const float*)d_in[4];
  const float* cb2 = (const float*)d_in[5];
  const float* cw3 = (const float*)d_in[6];
  const float* cb3 = (const float*)d_in[7];
  const float *gw[5], *gb[5], *bng[5], *bnb[5], *bnm[5], *bnv[5];
  for (int l = 0; l < 5; l++) {
    gw[l]  = (const float*)d_in[8 + 6 * l + 0];
    gb[l]  = (const float*)d_in[8 + 6 * l + 1];
    bng[l] = (const float*)d_in[8 + 6 * l + 2];
    bnb[l] = (const float*)d_in[8 + 6 * l + 3];
    bnm[l] = (const float*)d_in[8 + 6 * l + 4];
    bnv[l] = (const float*)d_in[8 + 6 * l + 5];
  }
  const int* srcp = ei;
  const int* dstp = ei + NE;

  char* w = (char*)d_ws;
  auto alloc = [&](size_t bytes) { char* p = w; w += (bytes + 255) & ~255ULL; return p; };
  int*   deg     = (int*)alloc((size_t)NN * 4);
  int*   offsets = (int*)alloc((size_t)NN * 4);
  int*   cursor  = (int*)alloc((size_t)NN * 4);
  int*   counter = (int*)alloc(256);
  float* dinv    = (float*)alloc((size_t)NN * 4);
  int*   adj_src = (int*)alloc((size_t)NE * 4);
  float* adj_nm  = (float*)alloc((size_t)NE * 4);
  float* w1p     = (float*)alloc(96 * 128 * 4);
  float* bufA    = (float*)alloc((size_t)NN * 128 * 4);
  float* bufB    = (float*)alloc((size_t)NN * 128 * 4);
  float* bufC    = (float*)alloc((size_t)NN * 128 * 4);
  // total ~168 MB of d_ws

  int nb_n = (NN + 255) / 256;
  int nb_e = (NE + 255) / 256;
  k_init<<<nb_n, 256, 0, stream>>>(deg, counter, NN);
  k_count<<<nb_e, 256, 0, stream>>>(dstp, deg, NE);
  k_alloc<<<nb_n, 256, 0, stream>>>(deg, dinv, offsets, cursor, counter, NN);
  k_fill<<<nb_e, 256, 0, stream>>>(srcp, dstp, dinv, cursor, adj_src, adj_nm, NE);
  k_padw1<<<48, 256, 0, stream>>>(gw[0], w1p);

  k_cnn<<<(NN + 3) / 4, 256, 0, stream>>>(x, cw1, cb1, cw2, cb2, cw3, cb3, bufA, NN);

  int gx = (NN + 63) / 64;
  // L1: H[N,96] @ W1p[96,128] -> agg(FO=128) tanh
  k_gemm<96, 128, 64><<<dim3(gx, 2), 256, 0, stream>>>(bufA, w1p, bufB, NN);
  k_agg<128, false><<<(NN + 1) / 2, 256, 0, stream>>>(bufB, offsets, deg, adj_src, adj_nm, dinv,
                                                      gb[0], bng[0], bnb[0], bnm[0], bnv[0], bufC, NN);
  // L2: [N,128]@[128,128]
  k_gemm<128, 128, 64><<<dim3(gx, 2), 256, 0, stream>>>(bufC, gw[1], bufB, NN);
  k_agg<128, false><<<(NN + 1) / 2, 256, 0, stream>>>(bufB, offsets, deg, adj_src, adj_nm, dinv,
                                                      gb[1], bng[1], bnb[1], bnm[1], bnv[1], bufA, NN);
  // L3: [N,128]@[128,64]
  k_gemm<128, 64, 64><<<dim3(gx, 1), 256, 0, stream>>>(bufA, gw[2], bufB, NN);
  k_agg<64, false><<<(NN + 3) / 4, 256, 0, stream>>>(bufB, offsets, deg, adj_src, adj_nm, dinv,
                                                     gb[2], bng[2], bnb[2], bnm[2], bnv[2], bufC, NN);
  // L4: [N,64]@[64,64]
  k_gemm<64, 64, 64><<<dim3(gx, 1), 256, 0, stream>>>(bufC, gw[3], bufB, NN);
  k_agg<64, false><<<(NN + 3) / 4, 256, 0, stream>>>(bufB, offsets, deg, adj_src, adj_nm, dinv,
                                                     gb[3], bng[3], bnb[3], bnm[3], bnv[3], bufA, NN);
  // L5: [N,64]@[64,16] -> agg + BN + softmax -> d_out
  k_gemm<64, 16, 16><<<dim3(gx, 1), 256, 0, stream>>>(bufA, gw[4], bufB, NN);
  k_agg<16, true><<<(NN + 15) / 16, 256, 0, stream>>>(bufB, offsets, deg, adj_src, adj_nm, dinv,
                                                      gb[4], bng[4], bnb[4], bnm[4], bnv[4], (float*)d_out, NN);
}

// Round 2
// 2472.577 us; speedup vs baseline: 1.1456x; 1.1456x over previous
//
#include <hip/hip_runtime.h>
#include <math.h>

namespace {

constexpr int NN = 100000;
constexpr int NE = 1600000;
constexpr float EPS = 1e-5f;

__device__ __forceinline__ float leaky(float x) { return x > 0.f ? x : 0.01f * x; }

// ---------------- preprocessing: degrees, dinv, CSR-by-dst ----------------

__global__ __launch_bounds__(256) void k_init(int* __restrict__ deg, int* __restrict__ counter, int n) {
  int i = blockIdx.x * 256 + threadIdx.x;
  if (i < n) deg[i] = 1;          // self-loop
  if (i == 0) counter[0] = 0;
}

__global__ __launch_bounds__(256) void k_count(const int* __restrict__ dst, int* __restrict__ deg, int e) {
  int i = blockIdx.x * 256 + threadIdx.x;
  if (i < e) atomicAdd(&deg[dst[i]], 1);
}

// dinv = rsqrt(deg); allocate CSR slot ranges via wave-aggregated atomic
__global__ __launch_bounds__(256) void k_alloc(const int* __restrict__ deg, float* __restrict__ dinv,
                                               int* __restrict__ offsets, int* __restrict__ cursor,
                                               int* __restrict__ counter, int n) {
  int i = blockIdx.x * 256 + threadIdx.x;
  int lane = threadIdx.x & 63;
  int c = 0;
  if (i < n) {
    int d = deg[i];
    dinv[i] = rsqrtf((float)d);
    c = d - 1;                    // real in-edges only (self-loop handled analytically)
  }
  // wave inclusive scan
  int v = c;
#pragma unroll
  for (int s = 1; s < 64; s <<= 1) {
    int t = __shfl_up(v, s, 64);
    if (lane >= s) v += t;
  }
  int total = __shfl(v, 63, 64);
  int base = 0;
  if (lane == 63) base = atomicAdd(counter, total);
  base = __shfl(base, 63, 64);
  if (i < n) {
    int off = base + v - c;       // exclusive prefix
    offsets[i] = off;
    cursor[i] = off;
  }
}

__global__ __launch_bounds__(256) void k_fill(const int* __restrict__ src, const int* __restrict__ dst,
                                              const float* __restrict__ dinv, int* __restrict__ cursor,
                                              int* __restrict__ adj_src, float* __restrict__ adj_norm, int e) {
  int i = blockIdx.x * 256 + threadIdx.x;
  if (i < e) {
    int s = src[i], d = dst[i];
    int p = atomicAdd(&cursor[d], 1);
    adj_src[p] = s;
    adj_norm[p] = dinv[s] * dinv[d];
  }
}

// zero-pad gw1 [94][128] -> [96][128]
__global__ __launch_bounds__(256) void k_padw1(const float* __restrict__ gw1, float* __restrict__ w1p) {
  int i = blockIdx.x * 256 + threadIdx.x;
  if (i < 96 * 128) w1p[i] = (i < 94 * 128) ? gw1[i] : 0.f;
}

// ---------------- CNN encoder ----------------
// per node: in [1][100][5] -> conv(10,3x3)+leaky -> conv(20,3x2)+leaky -> conv(1,3x2) -> tanh
// -> H[94] (stride 96, cols 94,95 = 0)
// block = 256 threads = 2 nodes x 128 threads. LDS ~64 KB -> 2 blocks/CU = 8 waves/CU.
__global__ __launch_bounds__(256) void k_cnn(const float* __restrict__ x,
                                             const float* __restrict__ cw1, const float* __restrict__ cb1,
                                             const float* __restrict__ cw2, const float* __restrict__ cb2,
                                             const float* __restrict__ cw3, const float* __restrict__ cb3,
                                             float* __restrict__ H, int n) {
  __shared__ float w1s[90];
  __shared__ float b1s[10];
  __shared__ float w2s[1200];
  __shared__ float b2s[20];
  __shared__ float w3s[120];
  __shared__ float b3s;
  __shared__ __align__(16) float inb[2][500];
  __shared__ float c1[2][2940];   // [10][98][3]
  __shared__ float c2[2][3840];   // [20][96][2]

  int tid = threadIdx.x;
  if (tid < 90) w1s[tid] = cw1[tid];
  if (tid < 10) b1s[tid] = cb1[tid];
  for (int i = tid; i < 1200; i += 256) w2s[i] = cw2[i];
  if (tid < 20) b2s[tid] = cb2[tid];
  if (tid < 120) w3s[tid] = cw3[tid];
  if (tid == 0) b3s = cb3[0];

  int half = tid >> 7;          // which node in block
  int nt = tid & 127;           // thread id within node
  int node = blockIdx.x * 2 + half;
  bool active = node < n;

  if (active && nt < 125) {
    const float4* xp = (const float4*)(x + (size_t)node * 500);
    ((float4*)inb[half])[nt] = xp[nt];
  }
  __syncthreads();

  if (active) {
    // conv1: positions p=(h,w) over 98x3, all 10 co per thread
    const float* in = inb[half];
    float* c1p = c1[half];
    for (int p = nt; p < 294; p += 128) {
      int h = p / 3, w = p - h * 3;
      float xv[9];
#pragma unroll
      for (int kh = 0; kh < 3; kh++)
#pragma unroll
        for (int kw = 0; kw < 3; kw++) xv[kh * 3 + kw] = in[(h + kh) * 5 + w + kw];
#pragma unroll
      for (int co = 0; co < 10; co++) {
        float a = b1s[co];
#pragma unroll
        for (int q = 0; q < 9; q++) a += xv[q] * w1s[co * 9 + q];
        c1p[co * 294 + p] = leaky(a);
      }
    }
  }
  __syncthreads();

  if (active) {
    // conv2: thread tile = 3h x 2w x 5co; 32 h-groups x 4 co-groups = 128 threads
    float* c1p = c1[half];
    float* c2p = c2[half];
    int hg = nt & 31, cog = nt >> 5;
    int h0 = hg * 3, co0 = cog * 5;
    float acc[3][2][5];
#pragma unroll
    for (int a = 0; a < 3; a++)
#pragma unroll
      for (int b = 0; b < 2; b++)
#pragma unroll
        for (int c = 0; c < 5; c++) acc[a][b][c] = 0.f;
#pragma unroll 1
    for (int ci = 0; ci < 10; ci++) {
      float r[5][3];
      const float* base = c1p + ci * 294 + h0 * 3;
#pragma unroll
      for (int i = 0; i < 5; i++)
#pragma unroll
        for (int j = 0; j < 3; j++) r[i][j] = base[i * 3 + j];
      float wt[5][6];
#pragma unroll
      for (int c = 0; c < 5; c++)
#pragma unroll
        for (int q = 0; q < 6; q++) wt[c][q] = w2s[((co0 + c) * 10 + ci) * 6 + q];
#pragma unroll
      for (int hh = 0; hh < 3; hh++)
#pragma unroll
        for (int w = 0; w < 2; w++)
#pragma unroll
          for (int c = 0; c < 5; c++)
            acc[hh][w][c] += r[hh][w] * wt[c][0] + r[hh][w + 1] * wt[c][1]
                           + r[hh + 1][w] * wt[c][2] + r[hh + 1][w + 1] * wt[c][3]
                           + r[hh + 2][w] * wt[c][4] + r[hh + 2][w + 1] * wt[c][5];
    }
#pragma unroll
    for (int hh = 0; hh < 3; hh++)
#pragma unroll
      for (int w = 0; w < 2; w++)
#pragma unroll
        for (int c = 0; c < 5; c++)
          c2p[((co0 + c) * 96 + h0 + hh) * 2 + w] = leaky(acc[hh][w][c] + b2s[co0 + c]);
  }
  __syncthreads();

  if (active) {
    // conv3 + tanh -> H ; one output row per thread (94 rows)
    float* c2p = c2[half];
    float* Hp = H + (size_t)node * 96;
    if (nt < 94) {
      float a = b3s;
#pragma unroll
      for (int ci = 0; ci < 20; ci++) {
        const float* cb = c2p + (ci * 96 + nt) * 2;
#pragma unroll
        for (int q = 0; q < 6; q++) a += cb[q] * w3s[ci * 6 + q];
      }
      Hp[nt] = tanhf(a);
    } else if (nt < 96) {
      Hp[nt] = 0.f;
    }
  }
}

// ---------------- GEMM: C[M,FO-tile] = A[M,K] @ W[K,FO] ----------------
template <int K, int FO, int BN>
__global__ __launch_bounds__(256) void k_gemm(const float* __restrict__ A, const float* __restrict__ W,
                                              float* __restrict__ C, int M) {
  __shared__ float As[64][K + 1];
  __shared__ __align__(16) float Ws[K][BN];
  int tid = threadIdx.x;
  int row_base = blockIdx.x * 64;
  int col_base = blockIdx.y * BN;

  for (int idx = tid; idx < 64 * K; idx += 256) {
    int r = idx / K, k = idx - r * K;
    int row = row_base + r;
    As[r][k] = (row < M) ? A[(size_t)row * K + k] : 0.f;
  }
  for (int idx = tid; idx < K * BN; idx += 256) {
    int r = idx / BN, c = idx - r * BN;
    Ws[r][c] = W[r * FO + col_base + c];
  }
  __syncthreads();

  if constexpr (BN == 64) {
    int ty = tid >> 4, tx = tid & 15;
    float acc[4][4] = {};
#pragma unroll 4
    for (int k = 0; k < K; k++) {
      float a0 = As[ty * 4 + 0][k];
      float a1 = As[ty * 4 + 1][k];
      float a2 = As[ty * 4 + 2][k];
      float a3 = As[ty * 4 + 3][k];
      const float4 b = *(const float4*)&Ws[k][tx * 4];
      acc[0][0] += a0 * b.x; acc[0][1] += a0 * b.y; acc[0][2] += a0 * b.z; acc[0][3] += a0 * b.w;
      acc[1][0] += a1 * b.x; acc[1][1] += a1 * b.y; acc[1][2] += a1 * b.z; acc[1][3] += a1 * b.w;
      acc[2][0] += a2 * b.x; acc[2][1] += a2 * b.y; acc[2][2] += a2 * b.z; acc[2][3] += a2 * b.w;
      acc[3][0] += a3 * b.x; acc[3][1] += a3 * b.y; acc[3][2] += a3 * b.z; acc[3][3] += a3 * b.w;
    }
#pragma unroll
    for (int i = 0; i < 4; i++) {
      int row = row_base + ty * 4 + i;
      if (row < M) {
        float4 v = make_float4(acc[i][0], acc[i][1], acc[i][2], acc[i][3]);
        *(float4*)&C[(size_t)row * FO + col_base + tx * 4] = v;
      }
    }
  } else {  // BN == 16: thread = 1 row x 4 cols
    int ty = tid >> 2, tx = tid & 3;
    float acc[4] = {};
#pragma unroll 4
    for (int k = 0; k < K; k++) {
      float a = As[ty][k];
      const float4 b = *(const float4*)&Ws[k][tx * 4];
      acc[0] += a * b.x; acc[1] += a * b.y; acc[2] += a * b.z; acc[3] += a * b.w;
    }
    int row = row_base + ty;
    if (row < M) *(float4*)&C[(size_t)row * FO + col_base + tx * 4] = make_float4(acc[0], acc[1], acc[2], acc[3]);
  }
}

// ---------------- aggregation + bias + BN (+tanh | +softmax) ----------------
template <int FO, bool SOFT>
__global__ __launch_bounds__(256) void k_agg(const float* __restrict__ XW,
                                             const int* __restrict__ offsets, const int* __restrict__ deg,
                                             const int* __restrict__ adj_src, const float* __restrict__ adj_norm,
                                             const float* __restrict__ dinv,
                                             const float* __restrict__ gb, const float* __restrict__ bg,
                                             const float* __restrict__ bb, const float* __restrict__ bm,
                                             const float* __restrict__ bv,
                                             float* __restrict__ out, int n) {
  constexpr int NPB = 256 / FO;
  int tid = threadIdx.x;
  int li = tid / FO, col = tid % FO;
  int node = blockIdx.x * NPB + li;
  if (node >= n) return;

  float dv = dinv[node];
  float acc = XW[(size_t)node * FO + col] * dv * dv;  // self-loop
  int start = offsets[node];
  int cnt = deg[node] - 1;
  for (int e = 0; e < cnt; e++) {
    int s = adj_src[start + e];
    float nm = adj_norm[start + e];
    acc += XW[(size_t)s * FO + col] * nm;
  }
  float scale = bg[col] * rsqrtf(bv[col] + EPS);
  float v = (acc + gb[col] - bm[col]) * scale + bb[col];
  if constexpr (SOFT) {
    float mx = v;
#pragma unroll
    for (int m = 8; m; m >>= 1) mx = fmaxf(mx, __shfl_xor(mx, m, 16));
    float ex = expf(v - mx);
    float sm = ex;
#pragma unroll
    for (int m = 8; m; m >>= 1) sm += __shfl_xor(sm, m, 16);
    out[(size_t)node * FO + col] = ex / sm;
  } else {
    out[(size_t)node * FO + col] = tanhf(v);
  }
}

}  // namespace

extern "C" void kernel_launch(void* const* d_in, const int* in_sizes, int n_in,
                              void* d_out, int out_size, void* d_ws, size_t ws_size,
                              hipStream_t stream) {
  const float* x   = (const float*)d_in[0];
  const int*   ei  = (const int*)d_in[1];
  const float* cw1 = (const float*)d_in[2];
  const float* cb1 = (const float*)d_in[3];
  const float* cw2 = (const float*)d_in[4];
  const float* cb2 = (const float*)d_in[5];
  const float* cw3 = (const float*)d_in[6];
  const float* cb3 = (const float*)d_in[7];
  const float *gw[5], *gb[5], *bng[5], *bnb[5], *bnm[5], *bnv[5];
  for (int l = 0; l < 5; l++) {
    gw[l]  = (const float*)d_in[8 + 6 * l + 0];
    gb[l]  = (const float*)d_in[8 + 6 * l + 1];
    bng[l] = (const float*)d_in[8 + 6 * l + 2];
    bnb[l] = (const float*)d_in[8 + 6 * l + 3];
    bnm[l] = (const float*)d_in[8 + 6 * l + 4];
    bnv[l] = (const float*)d_in[8 + 6 * l + 5];
  }
  const int* srcp = ei;
  const int* dstp = ei + NE;

  char* w = (char*)d_ws;
  auto alloc = [&](size_t bytes) { char* p = w; w += (bytes + 255) & ~255ULL; return p; };
  int*   deg     = (int*)alloc((size_t)NN * 4);
  int*   offsets = (int*)alloc((size_t)NN * 4);
  int*   cursor  = (int*)alloc((size_t)NN * 4);
  int*   counter = (int*)alloc(256);
  float* dinv    = (float*)alloc((size_t)NN * 4);
  int*   adj_src = (int*)alloc((size_t)NE * 4);
  float* adj_nm  = (float*)alloc((size_t)NE * 4);
  float* w1p     = (float*)alloc(96 * 128 * 4);
  float* bufA    = (float*)alloc((size_t)NN * 128 * 4);
  float* bufB    = (float*)alloc((size_t)NN * 128 * 4);
  float* bufC    = (float*)alloc((size_t)NN * 128 * 4);

  int nb_n = (NN + 255) / 256;
  int nb_e = (NE + 255) / 256;
  k_init<<<nb_n, 256, 0, stream>>>(deg, counter, NN);
  k_count<<<nb_e, 256, 0, stream>>>(dstp, deg, NE);
  k_alloc<<<nb_n, 256, 0, stream>>>(deg, dinv, offsets, cursor, counter, NN);
  k_fill<<<nb_e, 256, 0, stream>>>(srcp, dstp, dinv, cursor, adj_src, adj_nm, NE);
  k_padw1<<<48, 256, 0, stream>>>(gw[0], w1p);

  k_cnn<<<(NN + 1) / 2, 256, 0, stream>>>(x, cw1, cb1, cw2, cb2, cw3, cb3, bufA, NN);

  int gx = (NN + 63) / 64;
  // L1: H[N,96] @ W1p[96,128] -> agg(FO=128) tanh
  k_gemm<96, 128, 64><<<dim3(gx, 2), 256, 0, stream>>>(bufA, w1p, bufB, NN);
  k_agg<128, false><<<(NN + 1) / 2, 256, 0, stream>>>(bufB, offsets, deg, adj_src, adj_nm, dinv,
                                                      gb[0], bng[0], bnb[0], bnm[0], bnv[0], bufC, NN);
  // L2: [N,128]@[128,128]
  k_gemm<128, 128, 64><<<dim3(gx, 2), 256, 0, stream>>>(bufC, gw[1], bufB, NN);
  k_agg<128, false><<<(NN + 1) / 2, 256, 0, stream>>>(bufB, offsets, deg, adj_src, adj_nm, dinv,
                                                      gb[1], bng[1], bnb[1], bnm[1], bnv[1], bufA, NN);
  // L3: [N,128]@[128,64]
  k_gemm<128, 64, 64><<<dim3(gx, 1), 256, 0, stream>>>(bufA, gw[2], bufB, NN);
  k_agg<64, false><<<(NN + 3) / 4, 256, 0, stream>>>(bufB, offsets, deg, adj_src, adj_nm, dinv,
                                                     gb[2], bng[2], bnb[2], bnm[2], bnv[2], bufC, NN);
  // L4: [N,64]@[64,64]
  k_gemm<64, 64, 64><<<dim3(gx, 1), 256, 0, stream>>>(bufC, gw[3], bufB, NN);
  k_agg<64, false><<<(NN + 3) / 4, 256, 0, stream>>>(bufB, offsets, deg, adj_src, adj_nm, dinv,
                                                     gb[3], bng[3], bnb[3], bnm[3], bnv[3], bufA, NN);
  // L5: [N,64]@[64,16] -> agg + BN + softmax -> d_out
  k_gemm<64, 16, 16><<<dim3(gx, 1), 256, 0, stream>>>(bufA, gw[4], bufB, NN);
  k_agg<16, true><<<(NN + 15) / 16, 256, 0, stream>>>(bufB, offsets, deg, adj_src, adj_nm, dinv,
                                                      gb[4], bng[4], bnb[4], bnm[4], bnv[4], (float*)d_out, NN);
}